// Round 2
// baseline (187.498 us; speedup 1.0000x reference)
//
#include <hip/hip_runtime.h>
#include <hip/hip_bf16.h>

// Problem: CrossViewFusionModule
//   global_query: [B=16, D=256] f32
//   value:        [B=16, D=256, W=128, H=128] f32
//   q = l2norm(q, axis=-1); v = l2norm(value, axis=D)
//   score[b,wh] = sum_d q[b,d]*v[b,d,wh]
//   attn = (score - min_b) / (max_b - min_b + 1e-8)   (min/max over wh per b)
//   context = attn * v
//   outputs: (context [B,D,W,H], attn [B,1,W,H]) concatenated in d_out.

#define B_  16
#define D_  256
#define WH_ 16384   // 128*128
#define NCH 4       // D-split chunks (occupancy: 1024 blocks = 16 waves/CU)
#define DCH (D_ / NCH)

// ---- monotone float <-> sortable uint mapping (for exact atomic min/max) ----
__device__ __forceinline__ unsigned int fmap(float f) {
    unsigned int u = __float_as_uint(f);
    return (u & 0x80000000u) ? ~u : (u | 0x80000000u);
}
__device__ __forceinline__ float funmap(unsigned int u) {
    unsigned int b = (u & 0x80000000u) ? (u ^ 0x80000000u) : ~u;
    return __uint_as_float(b);
}

__global__ void init_mm_kernel(unsigned int* __restrict__ mm) {
    int i = threadIdx.x;
    if (i < 2 * B_) mm[i] = (i & 1) ? 0u : 0xFFFFFFFFu;  // even: min, odd: max
}

// Partial reduction over a 64-wide D-chunk.
// grid = (WH/1024, B*NCH), block = 256. Each thread: 4 wh (float4), 64 d iters.
__global__ __launch_bounds__(256) void score_part_kernel(
    const float* __restrict__ q, const float* __restrict__ value,
    float* __restrict__ pss, float* __restrict__ pdt)
{
    const int bc  = blockIdx.y;
    const int b   = bc >> 2;       // NCH == 4
    const int ch  = bc & 3;
    const int tid = threadIdx.x;
    __shared__ float qs[DCH];
    __shared__ float red[256];

    // q-row norm needs all 256 elements; keep only this chunk's 64 q-hats.
    float qv = q[b * D_ + tid];
    red[tid] = qv * qv;
    __syncthreads();
    for (int s = 128; s > 0; s >>= 1) {
        if (tid < s) red[tid] += red[tid + s];
        __syncthreads();
    }
    float qinv = 1.0f / fmaxf(sqrtf(red[0]), 1e-12f);
    int dd = tid - ch * DCH;
    if (dd >= 0 && dd < DCH) qs[dd] = qv * qinv;
    __syncthreads();

    const int wh0 = (blockIdx.x * 256 + tid) * 4;
    const float* vb = value + ((size_t)b * D_ + (size_t)ch * DCH) * WH_ + wh0;
    float ss0 = 0.f, ss1 = 0.f, ss2 = 0.f, ss3 = 0.f;
    float dt0 = 0.f, dt1 = 0.f, dt2 = 0.f, dt3 = 0.f;
#pragma unroll 8
    for (int d = 0; d < DCH; ++d) {
        float4 v4 = *(const float4*)(vb + (size_t)d * WH_);
        float qd = qs[d];
        ss0 += v4.x * v4.x; ss1 += v4.y * v4.y;
        ss2 += v4.z * v4.z; ss3 += v4.w * v4.w;
        dt0 += qd * v4.x;   dt1 += qd * v4.y;
        dt2 += qd * v4.z;   dt3 += qd * v4.w;
    }
    size_t o = (size_t)(ch * B_ + b) * WH_ + wh0;
    *(float4*)(pss + o) = make_float4(ss0, ss1, ss2, ss3);
    *(float4*)(pdt + o) = make_float4(dt0, dt1, dt2, dt3);
}

// Sum the NCH partials -> score, invn; block min/max -> atomics.
// grid = (WH/1024, B), block = 256.
__global__ __launch_bounds__(256) void combine_kernel(
    const float* __restrict__ pss, const float* __restrict__ pdt,
    float* __restrict__ score, float* __restrict__ invn,
    unsigned int* __restrict__ mm)
{
    const int b   = blockIdx.y;
    const int tid = threadIdx.x;
    const int wh0 = (blockIdx.x * 256 + tid) * 4;
    __shared__ float red[256];

    float ssx = 0.f, ssy = 0.f, ssz = 0.f, ssw = 0.f;
    float dtx = 0.f, dty = 0.f, dtz = 0.f, dtw = 0.f;
#pragma unroll
    for (int c = 0; c < NCH; ++c) {
        size_t o = (size_t)(c * B_ + b) * WH_ + wh0;
        float4 a = *(const float4*)(pss + o);
        float4 d = *(const float4*)(pdt + o);
        ssx += a.x; ssy += a.y; ssz += a.z; ssw += a.w;
        dtx += d.x; dty += d.y; dtz += d.z; dtw += d.w;
    }
    float n0 = 1.0f / fmaxf(sqrtf(ssx), 1e-12f);
    float n1 = 1.0f / fmaxf(sqrtf(ssy), 1e-12f);
    float n2 = 1.0f / fmaxf(sqrtf(ssz), 1e-12f);
    float n3 = 1.0f / fmaxf(sqrtf(ssw), 1e-12f);
    float s0 = dtx * n0, s1 = dty * n1, s2 = dtz * n2, s3 = dtw * n3;

    *(float4*)(score + (size_t)b * WH_ + wh0) = make_float4(s0, s1, s2, s3);
    *(float4*)(invn  + (size_t)b * WH_ + wh0) = make_float4(n0, n1, n2, n3);

    float mn = fminf(fminf(s0, s1), fminf(s2, s3));
    float mx = fmaxf(fmaxf(s0, s1), fmaxf(s2, s3));
    red[tid] = mn;
    __syncthreads();
    for (int s = 128; s > 0; s >>= 1) {
        if (tid < s) red[tid] = fminf(red[tid], red[tid + s]);
        __syncthreads();
    }
    float bmn = red[0];
    __syncthreads();
    red[tid] = mx;
    __syncthreads();
    for (int s = 128; s > 0; s >>= 1) {
        if (tid < s) red[tid] = fmaxf(red[tid], red[tid + s]);
        __syncthreads();
    }
    if (tid == 0) {
        atomicMin(&mm[2 * b],     fmap(bmn));
        atomicMax(&mm[2 * b + 1], fmap(red[0]));
    }
}

// context = attn * invn * value; attn emitted once (d==0 slice).
// grid = (256, B), block = 256; per-b grid-stride (16 iters/thread).
__global__ __launch_bounds__(256) void ctx_kernel(
    const float* __restrict__ value, const float* __restrict__ score,
    const float* __restrict__ invn, const unsigned int* __restrict__ mm,
    float* __restrict__ out_ctx, float* __restrict__ out_attn)
{
    const int b = blockIdx.y;
    const float mn = funmap(mm[2 * b]);
    const float sc = 1.0f / (funmap(mm[2 * b + 1]) - mn + 1e-8f);

    const float4* vb  = (const float4*)(value   + (size_t)b * D_ * WH_);
    float4*       cb  = (float4*)(out_ctx       + (size_t)b * D_ * WH_);
    const float4* s4p = (const float4*)(score   + (size_t)b * WH_);
    const float4* n4p = (const float4*)(invn    + (size_t)b * WH_);
    float4*       ab  = (float4*)(out_attn      + (size_t)b * WH_);

    const int N4 = D_ * WH_ / 4;           // 1,048,576 float4s per b
    const int stride = gridDim.x * blockDim.x;
    for (int i = blockIdx.x * blockDim.x + threadIdx.x; i < N4; i += stride) {
        int wh4 = i & (WH_ / 4 - 1);
        float4 v4 = vb[i];
        float4 s4 = s4p[wh4];
        float4 n4 = n4p[wh4];
        float4 a4;
        a4.x = (s4.x - mn) * sc; a4.y = (s4.y - mn) * sc;
        a4.z = (s4.z - mn) * sc; a4.w = (s4.w - mn) * sc;
        float4 c4;
        c4.x = a4.x * n4.x * v4.x; c4.y = a4.y * n4.y * v4.y;
        c4.z = a4.z * n4.z * v4.z; c4.w = a4.w * n4.w * v4.w;
        cb[i] = c4;
        if (i < WH_ / 4) ab[i] = a4;       // d == 0 slice
    }
}

extern "C" void kernel_launch(void* const* d_in, const int* in_sizes, int n_in,
                              void* d_out, int out_size, void* d_ws, size_t ws_size,
                              hipStream_t stream) {
    const float* q     = (const float*)d_in[0];   // [16,256]
    const float* value = (const float*)d_in[1];   // [16,256,128,128]

    float* out_ctx  = (float*)d_out;                       // B*D*WH floats
    float* out_attn = out_ctx + (size_t)B_ * D_ * WH_;     // B*WH floats

    // Partials staged INSIDE d_out's ctx region (8.4 MB of 268 MB); the ctx
    // pass fully overwrites it afterwards, stream order makes this safe.
    float* pss = out_ctx;                                   // NCH*B*WH floats
    float* pdt = out_ctx + (size_t)NCH * B_ * WH_;          // NCH*B*WH floats

    // workspace: score [B*WH] f32 | invn [B*WH] f32 | mm [2*B] u32  (~2.1 MB)
    float* score = (float*)d_ws;
    float* invn  = score + (size_t)B_ * WH_;
    unsigned int* mm = (unsigned int*)(invn + (size_t)B_ * WH_);

    hipLaunchKernelGGL(init_mm_kernel, dim3(1), dim3(64), 0, stream, mm);
    hipLaunchKernelGGL(score_part_kernel, dim3(WH_ / 1024, B_ * NCH), dim3(256),
                       0, stream, q, value, pss, pdt);
    hipLaunchKernelGGL(combine_kernel, dim3(WH_ / 1024, B_), dim3(256),
                       0, stream, pss, pdt, score, invn, mm);
    hipLaunchKernelGGL(ctx_kernel, dim3(256, B_), dim3(256), 0, stream,
                       value, score, invn, mm, out_ctx, out_attn);
}

// Round 3
// 136.125 us; speedup vs baseline: 1.3774x; 1.3774x over previous
//
#include <hip/hip_runtime.h>
#include <hip/hip_bf16.h>

// Problem: CrossViewFusionModule
//   global_query: [B=16, D=256] f32
//   value:        [B=16, D=256, W=128, H=128] f32
//   q = l2norm(q, axis=-1); v = l2norm(value, axis=D)
//   score[b,wh] = sum_d q[b,d]*v[b,d,wh]
//   attn = (score - min_b) / (max_b - min_b + 1e-8)   (min/max over wh per b)
//   context = attn * v
//   outputs: (context [B,D,W,H], attn [B,1,W,H]) concatenated in d_out.
//
// R3 strategy: value (268 MB) is ~one Infinity-Cache (256 MB) wide. Score pass
// streams it through L3; ctx pass re-reads it MIRRORED (d descending) so the
// most-recently-cached lines are consumed first, and writes its 269 MB output
// with NON-TEMPORAL stores so the write stream doesn't evict value from L2/L3.

#define B_  16
#define D_  256
#define WH_ 16384   // 128*128

// ---- monotone float <-> sortable uint mapping (for exact atomic min/max) ----
__device__ __forceinline__ unsigned int fmap(float f) {
    unsigned int u = __float_as_uint(f);
    return (u & 0x80000000u) ? ~u : (u | 0x80000000u);
}
__device__ __forceinline__ float funmap(unsigned int u) {
    unsigned int b = (u & 0x80000000u) ? (u ^ 0x80000000u) : ~u;
    return __uint_as_float(b);
}

typedef float f32x4_t __attribute__((ext_vector_type(4)));
__device__ __forceinline__ void nt_store4(float* p, float4 v) {
    f32x4_t w = {v.x, v.y, v.z, v.w};
    __builtin_nontemporal_store(w, (f32x4_t*)p);   // global_store_dwordx4 ... nt
}

__global__ void init_mm_kernel(unsigned int* __restrict__ mm) {
    int i = threadIdx.x;
    if (i < 2 * B_) mm[i] = (i & 1) ? 0u : 0xFFFFFFFFu;  // even: min, odd: max
}

// One block = 1024 contiguous wh positions of one b (256 threads x float4).
// grid = (WH/1024, B). d ascends 0..255 (defines the L3 recency order).
__global__ __launch_bounds__(256) void score_kernel(
    const float* __restrict__ q, const float* __restrict__ value,
    float* __restrict__ score, float* __restrict__ invn,
    unsigned int* __restrict__ mm)
{
    const int b   = blockIdx.y;
    const int tid = threadIdx.x;
    __shared__ float qs[D_];
    __shared__ float red[256];

    // ---- normalize q row in LDS ----
    float qv = q[b * D_ + tid];
    red[tid] = qv * qv;
    __syncthreads();
    for (int s = 128; s > 0; s >>= 1) {
        if (tid < s) red[tid] += red[tid + s];
        __syncthreads();
    }
    float qnorm2 = red[0];
    __syncthreads();
    qs[tid] = qv * (1.0f / fmaxf(sqrtf(qnorm2), 1e-12f));
    __syncthreads();

    // ---- per-thread: 4 wh columns, reduce over D ----
    const int wh0 = (blockIdx.x * 256 + tid) * 4;
    const float* vb = value + (size_t)b * D_ * WH_ + wh0;
    float ss0 = 0.f, ss1 = 0.f, ss2 = 0.f, ss3 = 0.f;
    float dt0 = 0.f, dt1 = 0.f, dt2 = 0.f, dt3 = 0.f;
#pragma unroll 4
    for (int d = 0; d < D_; ++d) {
        float4 v4 = *(const float4*)(vb + (size_t)d * WH_);
        float qd = qs[d];
        ss0 += v4.x * v4.x; ss1 += v4.y * v4.y;
        ss2 += v4.z * v4.z; ss3 += v4.w * v4.w;
        dt0 += qd * v4.x;   dt1 += qd * v4.y;
        dt2 += qd * v4.z;   dt3 += qd * v4.w;
    }
    float n0 = 1.0f / fmaxf(sqrtf(ss0), 1e-12f);
    float n1 = 1.0f / fmaxf(sqrtf(ss1), 1e-12f);
    float n2 = 1.0f / fmaxf(sqrtf(ss2), 1e-12f);
    float n3 = 1.0f / fmaxf(sqrtf(ss3), 1e-12f);
    float s0 = dt0 * n0, s1 = dt1 * n1, s2 = dt2 * n2, s3 = dt3 * n3;

    *(float4*)(score + (size_t)b * WH_ + wh0) = make_float4(s0, s1, s2, s3);
    *(float4*)(invn  + (size_t)b * WH_ + wh0) = make_float4(n0, n1, n2, n3);

    // ---- block min/max -> one atomic pair per block ----
    float mn = fminf(fminf(s0, s1), fminf(s2, s3));
    float mx = fmaxf(fmaxf(s0, s1), fmaxf(s2, s3));
    red[tid] = mn;
    __syncthreads();
    for (int s = 128; s > 0; s >>= 1) {
        if (tid < s) red[tid] = fminf(red[tid], red[tid + s]);
        __syncthreads();
    }
    float bmn = red[0];
    __syncthreads();
    red[tid] = mx;
    __syncthreads();
    for (int s = 128; s > 0; s >>= 1) {
        if (tid < s) red[tid] = fmaxf(red[tid], red[tid + s]);
        __syncthreads();
    }
    if (tid == 0) {
        atomicMin(&mm[2 * b],     fmap(bmn));
        atomicMax(&mm[2 * b + 1], fmap(red[0]));
    }
}

// Mirrored elementwise pass. grid = (4 * WH/1024, B), block = 256.
// blockIdx.x = (dq << 4) | x : wh-span x (1024 positions, same spans as the
// score blocks), d-quarter dq walked DESCENDING (time-reverse of score's
// ascending-d traversal -> LRU-friendly L3 reuse of value).
// ctx/attn written with non-temporal stores (don't evict value from caches).
__global__ __launch_bounds__(256) void ctx_kernel(
    const float* __restrict__ value, const float* __restrict__ score,
    const float* __restrict__ invn, const unsigned int* __restrict__ mm,
    float* __restrict__ out_ctx, float* __restrict__ out_attn)
{
    const int x  = blockIdx.x & (WH_ / 1024 - 1);
    const int dq = blockIdx.x >> 4;                 // 0..3
    const int b  = blockIdx.y;
    const int wh0 = (x * 256 + threadIdx.x) * 4;

    const float mn = funmap(mm[2 * b]);
    const float sc = 1.0f / (funmap(mm[2 * b + 1]) - mn + 1e-8f);

    // wh is fixed per thread -> score/invn loaded ONCE, attn computed once.
    float4 s4 = *(const float4*)(score + (size_t)b * WH_ + wh0);
    float4 n4 = *(const float4*)(invn  + (size_t)b * WH_ + wh0);
    float4 a4;
    a4.x = (s4.x - mn) * sc; a4.y = (s4.y - mn) * sc;
    a4.z = (s4.z - mn) * sc; a4.w = (s4.w - mn) * sc;
    if (dq == 0) nt_store4(out_attn + (size_t)b * WH_ + wh0, a4);

    const float an0 = a4.x * n4.x, an1 = a4.y * n4.y;
    const float an2 = a4.z * n4.z, an3 = a4.w * n4.w;

    const float* vb = value   + (size_t)b * D_ * WH_ + wh0;
    float*       cb = out_ctx + (size_t)b * D_ * WH_ + wh0;
#pragma unroll 4
    for (int d = dq * 64 + 63; d >= dq * 64; --d) {
        float4 v4 = *(const float4*)(vb + (size_t)d * WH_);
        float4 c4;
        c4.x = an0 * v4.x; c4.y = an1 * v4.y;
        c4.z = an2 * v4.z; c4.w = an3 * v4.w;
        nt_store4(cb + (size_t)d * WH_, c4);
    }
}

extern "C" void kernel_launch(void* const* d_in, const int* in_sizes, int n_in,
                              void* d_out, int out_size, void* d_ws, size_t ws_size,
                              hipStream_t stream) {
    const float* q     = (const float*)d_in[0];   // [16,256]
    const float* value = (const float*)d_in[1];   // [16,256,128,128]

    float* out_ctx  = (float*)d_out;                       // B*D*WH floats
    float* out_attn = out_ctx + (size_t)B_ * D_ * WH_;     // B*WH floats

    // workspace: score [B*WH] f32 | invn [B*WH] f32 | mm [2*B] u32  (~2.1 MB)
    float* score = (float*)d_ws;
    float* invn  = score + (size_t)B_ * WH_;
    unsigned int* mm = (unsigned int*)(invn + (size_t)B_ * WH_);

    hipLaunchKernelGGL(init_mm_kernel, dim3(1), dim3(64), 0, stream, mm);
    hipLaunchKernelGGL(score_kernel, dim3(WH_ / 1024, B_), dim3(256), 0, stream,
                       q, value, score, invn, mm);
    hipLaunchKernelGGL(ctx_kernel, dim3(4 * (WH_ / 1024), B_), dim3(256),
                       0, stream, value, score, invn, mm, out_ctx, out_attn);
}